// Round 1
// baseline (197.279 us; speedup 1.0000x reference)
//
#include <hip/hip_runtime.h>

#define NQ 4096
#define NS 2048
#define DD 1024
#define HH 3
#define PP 256
#define CC 100

typedef __attribute__((ext_vector_type(8))) short bf16x8;
typedef __attribute__((ext_vector_type(4))) float f32x4;

#define AS1 __attribute__((address_space(1)))
#define AS3 __attribute__((address_space(3)))

__device__ __forceinline__ void gload16(const void* g, void* l) {
  __builtin_amdgcn_global_load_lds((const AS1 unsigned int*)g,
                                   (AS3 unsigned int*)l, 16, 0, 0);
}

__device__ __forceinline__ unsigned short f2bf(float f) {
  union { float f; unsigned u; } v; v.f = f;
  unsigned r = (v.u + 0x7FFFu + ((v.u >> 16) & 1u)) >> 16;
  return (unsigned short)r;
}

// ---------------------------------------------------------------------------
// prep: mean(query)->Xq bf16 ; support->Xs bf16 ; head_W -> Wt[h][p][k] bf16 ;
//       cls_W -> WcT[n][k] bf16 (padded to 128 rows with zeros)
// ---------------------------------------------------------------------------
__global__ __launch_bounds__(256) void prep_kernel(
    const float* __restrict__ q,      // [4][4096][1024]
    const float* __restrict__ sup,    // [2048][1024]
    const float* __restrict__ hW,     // [3][1024][256]
    const float* __restrict__ cW,     // [1024][100]
    unsigned short* __restrict__ Xq,  // [4096][1024]
    unsigned short* __restrict__ Xs,  // [2048][1024]
    unsigned short* __restrict__ Wt,  // [3][256][1024]
    unsigned short* __restrict__ WcT) // [128][1024]
{
  const int U0 = (NQ * DD) / 4;
  const int U1 = (NS * DD) / 4;
  const int U2 = (HH * PP * DD) / 4;
  const int U3 = (128 * DD) / 4;
  const int total = U0 + U1 + U2 + U3;
  for (int u = blockIdx.x * blockDim.x + threadIdx.x; u < total;
       u += gridDim.x * blockDim.x) {
    if (u < U0) {
      int i = u * 4;
      const float4 a = *(const float4*)&q[i];
      const float4 b = *(const float4*)&q[NQ * DD + i];
      const float4 c = *(const float4*)&q[2 * NQ * DD + i];
      const float4 d = *(const float4*)&q[3 * NQ * DD + i];
      ushort4 o;
      o.x = f2bf((a.x + b.x + c.x + d.x) * 0.25f);
      o.y = f2bf((a.y + b.y + c.y + d.y) * 0.25f);
      o.z = f2bf((a.z + b.z + c.z + d.z) * 0.25f);
      o.w = f2bf((a.w + b.w + c.w + d.w) * 0.25f);
      *(ushort4*)&Xq[i] = o;
    } else if (u < U0 + U1) {
      int i = (u - U0) * 4;
      const float4 a = *(const float4*)&sup[i];
      ushort4 o;
      o.x = f2bf(a.x); o.y = f2bf(a.y); o.z = f2bf(a.z); o.w = f2bf(a.w);
      *(ushort4*)&Xs[i] = o;
    } else if (u < U0 + U1 + U2) {
      int i4 = (u - (U0 + U1)) * 4;
      int k0 = i4 & (DD - 1);
      int p  = (i4 >> 10) & (PP - 1);
      int h  = i4 >> 18;
      ushort4 o;
      o.x = f2bf(hW[(h * DD + k0 + 0) * PP + p]);
      o.y = f2bf(hW[(h * DD + k0 + 1) * PP + p]);
      o.z = f2bf(hW[(h * DD + k0 + 2) * PP + p]);
      o.w = f2bf(hW[(h * DD + k0 + 3) * PP + p]);
      *(ushort4*)&Wt[(h * PP + p) * DD + k0] = o;
    } else {
      int i4 = (u - (U0 + U1 + U2)) * 4;
      int k0 = i4 & (DD - 1);
      int n  = i4 >> 10;
      ushort4 o;
      if (n < CC) {
        o.x = f2bf(cW[(k0 + 0) * CC + n]);
        o.y = f2bf(cW[(k0 + 1) * CC + n]);
        o.z = f2bf(cW[(k0 + 2) * CC + n]);
        o.w = f2bf(cW[(k0 + 3) * CC + n]);
      } else {
        o.x = 0; o.y = 0; o.z = 0; o.w = 0;
      }
      *(ushort4*)&WcT[n * DD + k0] = o;
    }
  }
}

// ---------------------------------------------------------------------------
// proj: for each head h, C = X @ W[h] + b[h], row-l2-normalize, write bf16 to
//       Qn[n][h*256+p] / Sn[m][h*256+p].  BM=64, BN=256(=P), BK=64, 4 waves.
// ---------------------------------------------------------------------------
__global__ __launch_bounds__(256) void proj_kernel(
    const unsigned short* __restrict__ Xq,
    const unsigned short* __restrict__ Xs,
    const unsigned short* __restrict__ Wt,
    const float* __restrict__ hb,      // [3][256]
    unsigned short* __restrict__ Qn,   // [4096][768]
    unsigned short* __restrict__ Sn)   // [2048][768]
{
  __shared__ unsigned short As[64 * 64];
  __shared__ unsigned short Bs[256 * 64];
  __shared__ float rowsq[4][64];

  const int bid = blockIdx.x;
  const int h = bid / 96;
  const int r = bid % 96;
  const unsigned short* src;
  unsigned short* dst;
  int row0;
  if (r < 64) { src = Xq; dst = Qn; row0 = r * 64; }
  else        { src = Xs; dst = Sn; row0 = (r - 64) * 64; }

  const int tid = threadIdx.x;
  const int w = tid >> 6;
  const int l = tid & 63;
  const int rA = l & 15;
  const int kg = l >> 4;

  f32x4 acc[4][4] = {};

  const unsigned short* wbase = Wt + h * PP * DD;

  for (int kt = 0; kt < DD / 64; ++kt) {
    __syncthreads();
    #pragma unroll
    for (int i = 0; i < 10; ++i) {
      int c = w + i * 4;
      const unsigned short* g;
      unsigned short* ldsu;
      if (c < 8) {
        g = src + (row0 + c * 8 + (l >> 3)) * DD + kt * 64 + (l & 7) * 8;
        ldsu = &As[c * 512];
      } else {
        int cb2 = c - 8;
        g = wbase + (cb2 * 8 + (l >> 3)) * DD + kt * 64 + (l & 7) * 8;
        ldsu = &Bs[cb2 * 512];
      }
      gload16(g, ldsu);
    }
    __syncthreads();
    #pragma unroll
    for (int kk = 0; kk < 2; ++kk) {
      bf16x8 a[4], b[4];
      #pragma unroll
      for (int mi = 0; mi < 4; ++mi)
        a[mi] = *(const bf16x8*)&As[(mi * 16 + rA) * 64 + kk * 32 + kg * 8];
      #pragma unroll
      for (int ni = 0; ni < 4; ++ni)
        b[ni] = *(const bf16x8*)&Bs[(w * 64 + ni * 16 + rA) * 64 + kk * 32 + kg * 8];
      #pragma unroll
      for (int mi = 0; mi < 4; ++mi)
        #pragma unroll
        for (int ni = 0; ni < 4; ++ni)
          acc[mi][ni] =
              __builtin_amdgcn_mfma_f32_16x16x32_bf16(a[mi], b[ni], acc[mi][ni], 0, 0, 0);
    }
  }

  // bias + per-row sum of squares (wave covers 64 rows x 64 cols)
  float bias[4];
  #pragma unroll
  for (int ni = 0; ni < 4; ++ni)
    bias[ni] = hb[h * PP + w * 64 + ni * 16 + rA];

  #pragma unroll
  for (int mi = 0; mi < 4; ++mi) {
    #pragma unroll
    for (int i = 0; i < 4; ++i) {
      float s = 0.f;
      #pragma unroll
      for (int ni = 0; ni < 4; ++ni) {
        float v = acc[mi][ni][i] + bias[ni];
        acc[mi][ni][i] = v;
        s += v * v;
      }
      s += __shfl_xor(s, 1);
      s += __shfl_xor(s, 2);
      s += __shfl_xor(s, 4);
      s += __shfl_xor(s, 8);
      if (rA == 0) rowsq[w][mi * 16 + kg * 4 + i] = s;
    }
  }
  __syncthreads();
  #pragma unroll
  for (int mi = 0; mi < 4; ++mi) {
    #pragma unroll
    for (int i = 0; i < 4; ++i) {
      int row = mi * 16 + kg * 4 + i;
      float tot = rowsq[0][row] + rowsq[1][row] + rowsq[2][row] + rowsq[3][row];
      float inv = 1.f / fmaxf(sqrtf(tot), 1e-8f);
      #pragma unroll
      for (int ni = 0; ni < 4; ++ni) {
        int col = h * PP + w * 64 + ni * 16 + rA;
        dst[(row0 + row) * (HH * PP) + col] = f2bf(acc[mi][ni][i] * inv);
      }
    }
  }
}

// ---------------------------------------------------------------------------
// mm: blocks 0..511  -> match_scores = (Qn @ Sn^T)/3   [4096][2048] f32
//     blocks 512..527-> support_preds = Xs @ WcT^T + b [2048][100]  f32
//     BM=BN=128, BK=64, 4 waves (2x2), 16x16x32 bf16 MFMA (m97 structure)
// ---------------------------------------------------------------------------
__global__ __launch_bounds__(256) void mm_kernel(
    const unsigned short* __restrict__ Qn,
    const unsigned short* __restrict__ Sn,
    const unsigned short* __restrict__ Xs,
    const unsigned short* __restrict__ WcT,
    const float* __restrict__ cb,
    float* __restrict__ out)
{
  __shared__ unsigned short As[128 * 64];
  __shared__ unsigned short Bs[128 * 64];

  const int bid = blockIdx.x;
  const int tid = threadIdx.x;
  const int w = tid >> 6;
  const int l = tid & 63;
  const int wm = w >> 1, wn = w & 1;
  const int rA = l & 15, kg = l >> 4;

  const unsigned short *A, *B;
  int ldk, nkt, bm, bn;
  const bool match = bid < 512;
  if (match) {
    bm = bid & 31; bn = bid >> 5;
    A = Qn + bm * 128 * (HH * PP);
    B = Sn + bn * 128 * (HH * PP);
    ldk = HH * PP; nkt = (HH * PP) / 64;
  } else {
    bm = bid - 512; bn = 0;
    A = Xs + bm * 128 * DD;
    B = WcT;
    ldk = DD; nkt = DD / 64;
  }

  f32x4 acc[4][4] = {};

  for (int kt = 0; kt < nkt; ++kt) {
    __syncthreads();
    #pragma unroll
    for (int i = 0; i < 8; ++i) {
      int c = w + i * 4;
      const unsigned short* g;
      unsigned short* ldsu;
      if (c < 16) {
        g = A + (c * 8 + (l >> 3)) * ldk + kt * 64 + (l & 7) * 8;
        ldsu = &As[c * 512];
      } else {
        int cb2 = c - 16;
        g = B + (cb2 * 8 + (l >> 3)) * ldk + kt * 64 + (l & 7) * 8;
        ldsu = &Bs[cb2 * 512];
      }
      gload16(g, ldsu);
    }
    __syncthreads();
    #pragma unroll
    for (int kk = 0; kk < 2; ++kk) {
      bf16x8 a[4], b[4];
      #pragma unroll
      for (int mi = 0; mi < 4; ++mi)
        a[mi] = *(const bf16x8*)&As[(wm * 64 + mi * 16 + rA) * 64 + kk * 32 + kg * 8];
      #pragma unroll
      for (int ni = 0; ni < 4; ++ni)
        b[ni] = *(const bf16x8*)&Bs[(wn * 64 + ni * 16 + rA) * 64 + kk * 32 + kg * 8];
      #pragma unroll
      for (int mi = 0; mi < 4; ++mi)
        #pragma unroll
        for (int ni = 0; ni < 4; ++ni)
          acc[mi][ni] =
              __builtin_amdgcn_mfma_f32_16x16x32_bf16(a[mi], b[ni], acc[mi][ni], 0, 0, 0);
    }
  }

  if (match) {
    #pragma unroll
    for (int mi = 0; mi < 4; ++mi)
      #pragma unroll
      for (int i = 0; i < 4; ++i) {
        int row = bm * 128 + wm * 64 + mi * 16 + kg * 4 + i;
        #pragma unroll
        for (int ni = 0; ni < 4; ++ni) {
          int col = bn * 128 + wn * 64 + ni * 16 + rA;
          out[row * NS + col] = acc[mi][ni][i] * (1.f / 3.f);
        }
      }
  } else {
    float* o2 = out + (long)NQ * NS;
    #pragma unroll
    for (int mi = 0; mi < 4; ++mi)
      #pragma unroll
      for (int i = 0; i < 4; ++i) {
        int row = bm * 128 + wm * 64 + mi * 16 + kg * 4 + i;
        #pragma unroll
        for (int ni = 0; ni < 4; ++ni) {
          int col = wn * 64 + ni * 16 + rA;
          if (col < CC) o2[row * CC + col] = acc[mi][ni][i] + cb[col];
        }
      }
  }
}

// ---------------------------------------------------------------------------
extern "C" void kernel_launch(void* const* d_in, const int* in_sizes, int n_in,
                              void* d_out, int out_size, void* d_ws, size_t ws_size,
                              hipStream_t stream) {
  const float* q   = (const float*)d_in[0];
  const float* sup = (const float*)d_in[1];
  const float* hW  = (const float*)d_in[2];
  const float* hb  = (const float*)d_in[3];
  const float* cW  = (const float*)d_in[4];
  const float* cb  = (const float*)d_in[5];
  float* out = (float*)d_out;

  char* ws = (char*)d_ws;
  unsigned short* Xq  = (unsigned short*)(ws + 0);                 // 8 MiB
  unsigned short* Xs  = (unsigned short*)(ws + (8u  << 20));       // 4 MiB
  unsigned short* Wt  = (unsigned short*)(ws + (12u << 20));       // 1.5 MiB
  unsigned short* WcT = (unsigned short*)(ws + (12u << 20) + 1572864u); // 256 KiB
  unsigned short* Qn  = (unsigned short*)(ws + (14u << 20));       // 6 MiB
  unsigned short* Sn  = (unsigned short*)(ws + (20u << 20));       // 3 MiB

  prep_kernel<<<2048, 256, 0, stream>>>(q, sup, hW, cW, Xq, Xs, Wt, WcT);
  proj_kernel<<<288, 256, 0, stream>>>(Xq, Xs, Wt, hb, Qn, Sn);
  mm_kernel<<<512 + 16, 256, 0, stream>>>(Qn, Sn, Xs, WcT, cb, out);
}